// Round 4
// baseline (746.464 us; speedup 1.0000x reference)
//
#include <hip/hip_runtime.h>
#include <float.h>

#define D 64

typedef float f32x4 __attribute__((ext_vector_type(4)));
typedef _Float16 f16x8 __attribute__((ext_vector_type(8)));

// numpy pairwise_sum (n=64): 8 stride-interleaved accumulators, tree combine;
// squares rounded separately. Verified bit-exact vs reference in prior rounds.
__device__ __forceinline__ float np_sum_sq_64(const float* v) {
  float s[8];
#pragma unroll
  for (int j = 0; j < 8; ++j) s[j] = __fmul_rn(v[j], v[j]);
#pragma unroll
  for (int b = 1; b < 8; ++b) {
#pragma unroll
    for (int j = 0; j < 8; ++j)
      s[j] = __fadd_rn(s[j], __fmul_rn(v[8 * b + j], v[8 * b + j]));
  }
  float t01 = __fadd_rn(s[0], s[1]);
  float t23 = __fadd_rn(s[2], s[3]);
  float t45 = __fadd_rn(s[4], s[5]);
  float t67 = __fadd_rn(s[6], s[7]);
  return __fadd_rn(__fadd_rn(t01, t23), __fadd_rn(t45, t67));
}

// pack two floats -> two fp16 (RN) in one u32
__device__ __forceinline__ unsigned int pkh(float a, float b) {
  union { _Float16 h[2]; unsigned int u; } x;
  x.h[0] = (_Float16)a;
  x.h[1] = (_Float16)b;
  return x.u;
}

// ---------------- Kernel A: c2[k] np-faithful + fp16 codebook (x1024 scaled,
// keeps all entries fp16-normal) + c2n = -512*c2 (exact) for acc-folding +
// transposed cbT4 for exact rescore.
__global__ __launch_bounds__(64) void vq_prep(
    const float* __restrict__ cb, unsigned short* __restrict__ cbh,
    float4* __restrict__ cbT4, float* __restrict__ c2,
    float* __restrict__ c2n, unsigned int* __restrict__ counters, int K) {
  if (blockIdx.x == 0 && threadIdx.x == 0) { counters[0] = 0u; counters[1] = 0u; }
  int k = blockIdx.x * 64 + threadIdx.x;
  if (k >= K) return;
  float row[D];
  const float4* cp = (const float4*)(cb + (size_t)k * D);
#pragma unroll
  for (int i = 0; i < 16; ++i) {
    float4 v = cp[i];
    row[4 * i] = v.x; row[4 * i + 1] = v.y;
    row[4 * i + 2] = v.z; row[4 * i + 3] = v.w;
    cbT4[(size_t)i * K + k] = v;  // transposed: [d/4][k], lanes k -> coalesced
    *(uint2*)(cbh + (size_t)k * D + 4 * i) =
        make_uint2(pkh(v.x * 1024.f, v.y * 1024.f),
                   pkh(v.z * 1024.f, v.w * 1024.f));
  }
  float c2v = np_sum_sq_64(row);
  c2[k] = c2v;
  c2n[k] = -512.0f * c2v;  // exact (pow-2 scale)
}

// ---------------- Kernel B: fp16 MFMA screen, top-3 tracking, fused gather.
// 4 waves x 64 rows, t-OUTER: each pass handles one 16-row tile over all 16
// chunks, so live state is ~50 VGPRs (no AGPR spill traffic). c2 is folded
// into the accumulator init (acc = -512*c2), and we track the MAX of
// F = dot_scaled - 512*c2 = -512*(dist - r2): per-score epilogue is
// and_or(id) + max + med3 + med3 only. FULL 10-bit code in low mantissa bits.
// Flag split (F-space, gaps scaled x512): g1-g2 < margin -> candidate pair;
// also g1-g3 < margin -> full exact rescore.
__global__ __launch_bounds__(256, 6) void vq_screen(
    const float* __restrict__ residual, const float* __restrict__ codebook,
    const unsigned short* __restrict__ cbh, const float* __restrict__ c2n,
    float* __restrict__ out_q, float* __restrict__ codes_f,
    unsigned int* __restrict__ counters, int* __restrict__ list,
    int N, int K) {
  __shared__ unsigned short smem[4096];  // 8 KB fp16 A tile (fragment-permuted)
  __shared__ float red[768];             // [wave][row(64)][3] triples
  __shared__ int code_lds[64];
  __shared__ float srow[64];             // per-row sum|r| for margin

  int tid = threadIdx.x;
  int rowbase = blockIdx.x * 64;

  // ---- stage 64 rows fp32 -> fp16, fragment-permuted; accumulate sum|r|
  float sr4[4];
#pragma unroll
  for (int jj = 0; jj < 4; ++jj) {
    int i = tid + 256 * jj;
    int r = i >> 4, d0 = (i & 15) * 4;
    float4 v = *(const float4*)(residual + (size_t)(rowbase + r) * D + d0);
    sr4[jj] = fabsf(v.x) + fabsf(v.y) + fabsf(v.z) + fabsf(v.w);
    int tile = r >> 4, rr = r & 15;
    int kblk = d0 >> 5, kk = d0 & 31;
    int lanep = rr + 16 * (kk >> 3);
    int off = ((tile * 2 + kblk) * 64 + lanep) * 8 + (kk & 7);
    *(uint2*)(smem + off) = make_uint2(pkh(v.x, v.y), pkh(v.z, v.w));
  }
#pragma unroll
  for (int jj = 0; jj < 4; ++jj) {
    float s = sr4[jj];
    s += __shfl_xor(s, 1, 64);
    s += __shfl_xor(s, 2, 64);
    s += __shfl_xor(s, 4, 64);
    s += __shfl_xor(s, 8, 64);
    sr4[jj] = s;
  }
  if ((tid & 15) == 0) {
#pragma unroll
    for (int jj = 0; jj < 4; ++jj) srow[(tid >> 4) + 16 * jj] = sr4[jj];
  }
  __syncthreads();

  int w = tid >> 6, lane = tid & 63;
  int lane15 = lane & 15, lq = lane >> 4;

#pragma unroll 1
  for (int t = 0; t < 4; ++t) {
    // A fragments for this 16-row tile (ds_read_b128 x2)
    f16x8 ah0 = *(const f16x8*)(smem + ((t * 2 + 0) * 64 + lane) * 8);
    f16x8 ah1 = *(const f16x8*)(smem + ((t * 2 + 1) * 64 + lane) * 8);

    float m1[4], m2[4], m3[4];
#pragma unroll
    for (int j = 0; j < 4; ++j) {
      m1[j] = -FLT_MAX; m2[j] = -FLT_MAX; m3[j] = -FLT_MAX;
    }

    const unsigned short* ph = cbh + (size_t)(w * 16 + lane15) * D + lq * 8;
    const float* pc2 = c2n + (w * 16 + lane15);

    // depth-2 B prefetch
    f16x8 B0a = *(const f16x8*)(ph);
    f16x8 B1a = *(const f16x8*)(ph + 32);
    float c2a = *pc2;
    ph += 64 * D; pc2 += 64;
    f16x8 B0b = *(const f16x8*)(ph);
    f16x8 B1b = *(const f16x8*)(ph + 32);
    float c2b = *pc2;

    unsigned int idb = (unsigned int)((w << 4) | lane15);  // + cc<<6 per chunk
    for (int cc = 0; cc < 16; ++cc) {
      f16x8 ch0 = B0a, ch1 = B1a;
      float q = c2a;
      B0a = B0b; B1a = B1b; c2a = c2b;
      if (cc < 14) {
        ph += 64 * D; pc2 += 64;
        B0b = *(const f16x8*)(ph);
        B1b = *(const f16x8*)(ph + 32);
        c2b = *pc2;
      }

      f32x4 a = {q, q, q, q};  // acc pre-loaded with -512*c2[code]
      a = __builtin_amdgcn_mfma_f32_16x16x32_f16(ah0, ch0, a, 0, 0, 0);
      a = __builtin_amdgcn_mfma_f32_16x16x32_f16(ah1, ch1, a, 0, 0, 0);
#pragma unroll
      for (int j = 0; j < 4; ++j) {
        // F = dot*1024 - 512*c2; maximize F <=> minimize dist. Full code in
        // low 10 mantissa bits: <=2^-13 relative shift, absorbed by margin;
        // exact ties always land within margin -> rescored exactly.
        float spf = __uint_as_float((__float_as_uint(a[j]) & 0xFFFFFC00u) | idb);
        float o1 = m1[j], o2 = m2[j];
        m3[j] = __builtin_amdgcn_fmed3f(o2, m3[j], spf);  // 3rd-largest
        m2[j] = __builtin_amdgcn_fmed3f(o1, o2, spf);     // 2nd-largest
        m1[j] = fmaxf(o1, spf);
      }
      idb += 64u;
    }

    // reduce across the 16 code-columns: merge sorted-desc triples
#pragma unroll
    for (int dlt = 1; dlt < 16; dlt <<= 1) {
#pragma unroll
      for (int j = 0; j < 4; ++j) {
        float a1 = m1[j], a2 = m2[j], a3 = m3[j];
        float b1 = __shfl_xor(a1, dlt, 64);
        float b2 = __shfl_xor(a2, dlt, 64);
        float b3 = __shfl_xor(a3, dlt, 64);
        m1[j] = fmaxf(a1, b1);
        m2[j] = fmaxf(fminf(a1, b1), fmaxf(a2, b2));
        m3[j] = fmaxf(fmaxf(fminf(a2, b1), fminf(a1, b2)), fmaxf(a3, b3));
      }
    }

    if (lane15 == 0) {
#pragma unroll
      for (int j = 0; j < 4; ++j) {
        int r = t * 16 + lq * 4 + j;
        int base = (w * 64 + r) * 3;
        red[base + 0] = m1[j];
        red[base + 1] = m2[j];
        red[base + 2] = m3[j];
      }
    }
    // no sync needed: each wave owns its red[w] slice and its A fragments
  }

  __syncthreads();
  if (tid < 64) {
    float a1 = red[tid * 3 + 0], a2 = red[tid * 3 + 1], a3 = red[tid * 3 + 2];
#pragma unroll
    for (int wv = 1; wv < 4; ++wv) {
      float b1 = red[(wv * 64 + tid) * 3 + 0];
      float b2 = red[(wv * 64 + tid) * 3 + 1];
      float b3 = red[(wv * 64 + tid) * 3 + 2];
      float n1 = fmaxf(a1, b1);
      float n2 = fmaxf(fminf(a1, b1), fmaxf(a2, b2));
      float n3 = fmaxf(fmaxf(fminf(a2, b1), fminf(a1, b2)), fmaxf(a3, b3));
      a1 = n1; a2 = n2; a3 = n3;
    }
    unsigned int u1 = __float_as_uint(a1);
    unsigned int u2 = __float_as_uint(a2);
    unsigned int u3 = __float_as_uint(a3);
    int ka = (int)(u1 & 1023u);
    float g1 = __uint_as_float(u1 & 0xFFFFFC00u);
    float g2 = __uint_as_float(u2 & 0xFFFFFC00u);
    float g3 = __uint_as_float(u3 & 0xFFFFFC00u);
    // margin in F-space = 512 * (4.6e-6*Sr + 4.0e-5)  [round-2-validated]
    float margin = __builtin_fmaf(srow[tid], 2.3552e-3f, 2.048e-2f);
    int row = rowbase + tid;
    code_lds[tid] = ka;
    float cf = (float)ka;
    if (g1 - g2 < margin) {
      if (g1 - g3 < margin) {  // clustered: full exact rescore
        unsigned int s = atomicAdd(counters + 0, 1u);
        list[s] = row;
      } else {  // exactly-2 candidates: stash (ka, kb) (exact < 2^20)
        unsigned int s = atomicAdd(counters + 1, 1u);
        list[N - 1 - (int)s] = row;
        cf = (float)(int)((unsigned int)ka | ((u2 & 1023u) << 10));
      }
    }
    codes_f[row] = cf;
  }
  __syncthreads();

  // ---- fused gather (pair/full kernels overwrite their rows if needed)
  for (int e = tid; e < 4096; e += 256) {
    int r = e >> 6, d = e & 63;
    out_q[(size_t)rowbase * D + e] = codebook[((size_t)code_lds[r] << 6) + d];
  }
}

// ---------------- Kernel C: exact np-faithful 2-candidate compare.
__global__ __launch_bounds__(256) void vq_pair(
    const float* __restrict__ residual, const float* __restrict__ codebook,
    const float* __restrict__ c2, float* __restrict__ codes_f,
    float* __restrict__ out_q, const unsigned int* __restrict__ counters,
    const int* __restrict__ list, int N) {
  unsigned int cnt = counters[1];
  for (unsigned int i = blockIdx.x * 256 + threadIdx.x; i < cnt;
       i += gridDim.x * 256) {
    int row = list[N - 1 - (int)i];
    int packed = (int)codes_f[row];
    int ka = packed & 1023, kb = packed >> 10;

    float r[D];
    const float4* rp = (const float4*)(residual + ((size_t)row << 6));
#pragma unroll
    for (int q = 0; q < 16; ++q) {
      float4 v = rp[q];
      r[4 * q] = v.x; r[4 * q + 1] = v.y; r[4 * q + 2] = v.z; r[4 * q + 3] = v.w;
    }
    float r2 = np_sum_sq_64(r);

    float da = 0.f, db = 0.f;
    const float4* ap = (const float4*)(codebook + ((size_t)ka << 6));
    const float4* bp = (const float4*)(codebook + ((size_t)kb << 6));
#pragma unroll
    for (int q = 0; q < 16; ++q) {
      float4 x = ap[q], y = bp[q];
      da = __fmaf_rn(r[4 * q + 0], x.x, da); db = __fmaf_rn(r[4 * q + 0], y.x, db);
      da = __fmaf_rn(r[4 * q + 1], x.y, da); db = __fmaf_rn(r[4 * q + 1], y.y, db);
      da = __fmaf_rn(r[4 * q + 2], x.z, da); db = __fmaf_rn(r[4 * q + 2], y.z, db);
      da = __fmaf_rn(r[4 * q + 3], x.w, da); db = __fmaf_rn(r[4 * q + 3], y.w, db);
    }
    float dista = __fsub_rn(__fadd_rn(r2, c2[ka]), __fmul_rn(2.0f, da));
    float distb = __fsub_rn(__fadd_rn(r2, c2[kb]), __fmul_rn(2.0f, db));
    bool bwin = (distb < dista) || (distb == dista && kb < ka);
    int win = bwin ? kb : ka;
    codes_f[row] = (float)win;  // always: replaces the packed stash
    if (bwin) {  // screen's gather wrote ka's row; fix it
      float4* oq = (float4*)(out_q + ((size_t)row << 6));
      const float4* cw = (const float4*)(codebook + ((size_t)win << 6));
#pragma unroll
      for (int q = 0; q < 16; ++q) oq[q] = cw[q];
    }
  }
}

// ---------------- Kernel D: exact np-faithful full rescore, fully coalesced.
__global__ __launch_bounds__(256) void vq_rescore(
    const float* __restrict__ residual, const float* __restrict__ codebook,
    const float4* __restrict__ cbT4, const float* __restrict__ c2,
    float* __restrict__ codes_f, float* __restrict__ out_q,
    const unsigned int* __restrict__ counters,
    const int* __restrict__ list, int K) {
  unsigned int cnt = counters[0];
  int w = threadIdx.x >> 6, lane = threadIdx.x & 63;
  unsigned int npairs = (cnt + 1) >> 1;
  for (unsigned int g = blockIdx.x * 4 + w; g < npairs; g += gridDim.x * 4) {
    int n0 = list[2 * g];
    bool two = (2 * g + 1 < cnt);
    int n1 = two ? list[2 * g + 1] : n0;

    float rl0 = residual[(size_t)n0 * D + lane];
    float rl1 = residual[(size_t)n1 * D + lane];

    int j = lane & 7;
    float x0 = __shfl(rl0, j, 64), x1 = __shfl(rl1, j, 64);
    float s0 = __fmul_rn(x0, x0), s1 = __fmul_rn(x1, x1);
#pragma unroll
    for (int b = 1; b < 8; ++b) {
      x0 = __shfl(rl0, 8 * b + j, 64);
      x1 = __shfl(rl1, 8 * b + j, 64);
      s0 = __fadd_rn(s0, __fmul_rn(x0, x0));
      s1 = __fadd_rn(s1, __fmul_rn(x1, x1));
    }
    s0 = __fadd_rn(s0, __shfl_xor(s0, 1, 64));
    s1 = __fadd_rn(s1, __shfl_xor(s1, 1, 64));
    s0 = __fadd_rn(s0, __shfl_xor(s0, 2, 64));
    s1 = __fadd_rn(s1, __shfl_xor(s1, 2, 64));
    s0 = __fadd_rn(s0, __shfl_xor(s0, 4, 64));
    s1 = __fadd_rn(s1, __shfl_xor(s1, 4, 64));
    float r2_0 = s0, r2_1 = s1;

    float m0[16], m1v[16];
#pragma unroll
    for (int ch = 0; ch < 16; ++ch) { m0[ch] = 0.f; m1v[ch] = 0.f; }

    for (int d4 = 0; d4 < 16; ++d4) {
      float a0 = __shfl(rl0, 4 * d4, 64), b0 = __shfl(rl0, 4 * d4 + 1, 64);
      float c0 = __shfl(rl0, 4 * d4 + 2, 64), e0 = __shfl(rl0, 4 * d4 + 3, 64);
      float a1 = __shfl(rl1, 4 * d4, 64), b1 = __shfl(rl1, 4 * d4 + 1, 64);
      float c1 = __shfl(rl1, 4 * d4 + 2, 64), e1 = __shfl(rl1, 4 * d4 + 3, 64);
      const float4* bp = cbT4 + (size_t)d4 * K + lane;
      float4 cbv[8];
#pragma unroll
      for (int h = 0; h < 2; ++h) {
#pragma unroll
        for (int q = 0; q < 8; ++q) cbv[q] = bp[(h * 8 + q) * 64];
#pragma unroll
        for (int q = 0; q < 8; ++q) {
          int ch = h * 8 + q;
          float4 c = cbv[q];
          float t0 = m0[ch], t1 = m1v[ch];
          t0 = __fmaf_rn(a0, c.x, t0); t1 = __fmaf_rn(a1, c.x, t1);
          t0 = __fmaf_rn(b0, c.y, t0); t1 = __fmaf_rn(b1, c.y, t1);
          t0 = __fmaf_rn(c0, c.z, t0); t1 = __fmaf_rn(c1, c.z, t1);
          t0 = __fmaf_rn(e0, c.w, t0); t1 = __fmaf_rn(e1, c.w, t1);
          m0[ch] = t0; m1v[ch] = t1;
        }
      }
    }

    float best0 = FLT_MAX, best1 = FLT_MAX;
    int bk0 = 0, bk1 = 0;
#pragma unroll
    for (int ch = 0; ch < 16; ++ch) {
      int code = ch * 64 + lane;
      float c2v = c2[code];
      float d0 = __fsub_rn(__fadd_rn(r2_0, c2v), __fmul_rn(2.0f, m0[ch]));
      float d1 = __fsub_rn(__fadd_rn(r2_1, c2v), __fmul_rn(2.0f, m1v[ch]));
      if (d0 < best0) { best0 = d0; bk0 = code; }
      if (d1 < best1) { best1 = d1; bk1 = code; }
    }
#pragma unroll
    for (int off = 32; off > 0; off >>= 1) {
      float ob = __shfl_down(best0, off, 64);
      int oi = __shfl_down(bk0, off, 64);
      if (ob < best0 || (ob == best0 && oi < bk0)) { best0 = ob; bk0 = oi; }
      ob = __shfl_down(best1, off, 64);
      oi = __shfl_down(bk1, off, 64);
      if (ob < best1 || (ob == best1 && oi < bk1)) { best1 = ob; bk1 = oi; }
    }
    int k0 = __shfl(bk0, 0, 64);
    int k1 = __shfl(bk1, 0, 64);
    if (lane == 0) codes_f[n0] = (float)k0;
    out_q[(size_t)n0 * D + lane] = codebook[((size_t)k0 << 6) + lane];
    if (two) {
      if (lane == 0) codes_f[n1] = (float)k1;
      out_q[(size_t)n1 * D + lane] = codebook[((size_t)k1 << 6) + lane];
    }
  }
}

extern "C" void kernel_launch(void* const* d_in, const int* in_sizes, int n_in,
                              void* d_out, int out_size, void* d_ws, size_t ws_size,
                              hipStream_t stream) {
  const float* residual = (const float*)d_in[0];
  const float* codebook = (const float*)d_in[1];
  int N = in_sizes[0] / D;
  int K = in_sizes[1] / D;

  float* out_q = (float*)d_out;
  float* codes_f = out_q + (size_t)N * D;

  // ws: c2[K] | c2n[K] | cbh fp16[K*D] | cbT4[K*D] | counters[2] | list[N]
  char* ws = (char*)d_ws;
  float* c2 = (float*)ws;
  float* c2n = (float*)(ws + (size_t)K * 4);
  unsigned short* cbh = (unsigned short*)(ws + (size_t)K * 8);
  float4* cbT4 = (float4*)(ws + (size_t)K * 8 + (size_t)K * D * 2);
  unsigned int* counters =
      (unsigned int*)(ws + (size_t)K * 8 + (size_t)K * D * 2 + (size_t)K * D * 4);
  int* list = (int*)(counters + 2);

  vq_prep<<<(K + 63) / 64, 64, 0, stream>>>(codebook, cbh, cbT4, c2, c2n,
                                            counters, K);

  vq_screen<<<N / 64, 256, 0, stream>>>(residual, codebook, cbh, c2n, out_q,
                                        codes_f, counters, list, N, K);

  vq_pair<<<512, 256, 0, stream>>>(residual, codebook, c2, codes_f, out_q,
                                   counters, list, N);

  vq_rescore<<<2048, 256, 0, stream>>>(residual, codebook, cbT4, c2, codes_f,
                                       out_q, counters, list, K);
}

// Round 5
// 525.929 us; speedup vs baseline: 1.4193x; 1.4193x over previous
//
#include <hip/hip_runtime.h>
#include <float.h>

#define D 64

typedef float f32x4 __attribute__((ext_vector_type(4)));
typedef _Float16 f16x8 __attribute__((ext_vector_type(8)));

// numpy pairwise_sum (n=64): 8 stride-interleaved accumulators, tree combine;
// squares rounded separately. Verified bit-exact vs reference in prior rounds.
__device__ __forceinline__ float np_sum_sq_64(const float* v) {
  float s[8];
#pragma unroll
  for (int j = 0; j < 8; ++j) s[j] = __fmul_rn(v[j], v[j]);
#pragma unroll
  for (int b = 1; b < 8; ++b) {
#pragma unroll
    for (int j = 0; j < 8; ++j)
      s[j] = __fadd_rn(s[j], __fmul_rn(v[8 * b + j], v[8 * b + j]));
  }
  float t01 = __fadd_rn(s[0], s[1]);
  float t23 = __fadd_rn(s[2], s[3]);
  float t45 = __fadd_rn(s[4], s[5]);
  float t67 = __fadd_rn(s[6], s[7]);
  return __fadd_rn(__fadd_rn(t01, t23), __fadd_rn(t45, t67));
}

// pack two floats -> two fp16 (RN) in one u32
__device__ __forceinline__ unsigned int pkh(float a, float b) {
  union { _Float16 h[2]; unsigned int u; } x;
  x.h[0] = (_Float16)a;
  x.h[1] = (_Float16)b;
  return x.u;
}

// ---------------- Kernel A: c2[k] np-faithful + fp16 codebook (x1024 scaled,
// keeps all entries fp16-normal) + c2n = -512*c2 (exact) for acc-folding +
// transposed cbT4 for exact rescore.
__global__ __launch_bounds__(64) void vq_prep(
    const float* __restrict__ cb, unsigned short* __restrict__ cbh,
    float4* __restrict__ cbT4, float* __restrict__ c2,
    float* __restrict__ c2n, unsigned int* __restrict__ counters, int K) {
  if (blockIdx.x == 0 && threadIdx.x == 0) { counters[0] = 0u; counters[1] = 0u; }
  int k = blockIdx.x * 64 + threadIdx.x;
  if (k >= K) return;
  float row[D];
  const float4* cp = (const float4*)(cb + (size_t)k * D);
#pragma unroll
  for (int i = 0; i < 16; ++i) {
    float4 v = cp[i];
    row[4 * i] = v.x; row[4 * i + 1] = v.y;
    row[4 * i + 2] = v.z; row[4 * i + 3] = v.w;
    cbT4[(size_t)i * K + k] = v;  // transposed: [d/4][k], lanes k -> coalesced
    *(uint2*)(cbh + (size_t)k * D + 4 * i) =
        make_uint2(pkh(v.x * 1024.f, v.y * 1024.f),
                   pkh(v.z * 1024.f, v.w * 1024.f));
  }
  float c2v = np_sum_sq_64(row);
  c2[k] = c2v;
  c2n[k] = -512.0f * c2v;  // exact (pow-2 scale)
}

// ---------------- Kernel B: fp16 MFMA screen, top-3 tracking, fused gather.
// 4 waves x 64 rows, t-OUTER: each pass handles one 16-row tile over all 16
// chunks, so live state is ~50 VGPRs. __launch_bounds__(256,4) = 128-VGPR
// budget: NO spill (round 4's (256,6) forced 40 VGPRs -> 2.1 GB scratch
// traffic). c2 folded into the accumulator init (acc = -512*c2); we track the
// MAX of F = dot_scaled - 512*c2: per-score epilogue is and_or(id) + max +
// med3 + med3 only. FULL 10-bit code in low mantissa bits.
// Flag split (F-space, gaps scaled x512): g1-g2 < margin -> candidate pair;
// also g1-g3 < margin -> full exact rescore.
__global__ __launch_bounds__(256, 4) void vq_screen(
    const float* __restrict__ residual, const float* __restrict__ codebook,
    const unsigned short* __restrict__ cbh, const float* __restrict__ c2n,
    float* __restrict__ out_q, float* __restrict__ codes_f,
    unsigned int* __restrict__ counters, int* __restrict__ list,
    int N, int K) {
  __shared__ unsigned short smem[4096];  // 8 KB fp16 A tile (fragment-permuted)
  __shared__ float red[768];             // [wave][row(64)][3] triples
  __shared__ int code_lds[64];
  __shared__ float srow[64];             // per-row sum|r| for margin

  int tid = threadIdx.x;
  int rowbase = blockIdx.x * 64;

  // ---- stage 64 rows fp32 -> fp16, fragment-permuted; accumulate sum|r|
  float sr4[4];
#pragma unroll
  for (int jj = 0; jj < 4; ++jj) {
    int i = tid + 256 * jj;
    int r = i >> 4, d0 = (i & 15) * 4;
    float4 v = *(const float4*)(residual + (size_t)(rowbase + r) * D + d0);
    sr4[jj] = fabsf(v.x) + fabsf(v.y) + fabsf(v.z) + fabsf(v.w);
    int tile = r >> 4, rr = r & 15;
    int kblk = d0 >> 5, kk = d0 & 31;
    int lanep = rr + 16 * (kk >> 3);
    int off = ((tile * 2 + kblk) * 64 + lanep) * 8 + (kk & 7);
    *(uint2*)(smem + off) = make_uint2(pkh(v.x, v.y), pkh(v.z, v.w));
  }
#pragma unroll
  for (int jj = 0; jj < 4; ++jj) {
    float s = sr4[jj];
    s += __shfl_xor(s, 1, 64);
    s += __shfl_xor(s, 2, 64);
    s += __shfl_xor(s, 4, 64);
    s += __shfl_xor(s, 8, 64);
    sr4[jj] = s;
  }
  if ((tid & 15) == 0) {
#pragma unroll
    for (int jj = 0; jj < 4; ++jj) srow[(tid >> 4) + 16 * jj] = sr4[jj];
  }
  __syncthreads();

  int w = tid >> 6, lane = tid & 63;
  int lane15 = lane & 15, lq = lane >> 4;

#pragma unroll 1
  for (int t = 0; t < 4; ++t) {
    // A fragments for this 16-row tile (ds_read_b128 x2)
    f16x8 ah0 = *(const f16x8*)(smem + ((t * 2 + 0) * 64 + lane) * 8);
    f16x8 ah1 = *(const f16x8*)(smem + ((t * 2 + 1) * 64 + lane) * 8);

    float m1[4], m2[4], m3[4];
#pragma unroll
    for (int j = 0; j < 4; ++j) {
      m1[j] = -FLT_MAX; m2[j] = -FLT_MAX; m3[j] = -FLT_MAX;
    }

    const unsigned short* ph = cbh + (size_t)(w * 16 + lane15) * D + lq * 8;
    const float* pc2 = c2n + (w * 16 + lane15);

    // depth-2 B prefetch
    f16x8 B0a = *(const f16x8*)(ph);
    f16x8 B1a = *(const f16x8*)(ph + 32);
    float c2a = *pc2;
    ph += 64 * D; pc2 += 64;
    f16x8 B0b = *(const f16x8*)(ph);
    f16x8 B1b = *(const f16x8*)(ph + 32);
    float c2b = *pc2;

    unsigned int idb = (unsigned int)((w << 4) | lane15);  // + cc<<6 per chunk
    for (int cc = 0; cc < 16; ++cc) {
      f16x8 ch0 = B0a, ch1 = B1a;
      float q = c2a;
      B0a = B0b; B1a = B1b; c2a = c2b;
      if (cc < 14) {
        ph += 64 * D; pc2 += 64;
        B0b = *(const f16x8*)(ph);
        B1b = *(const f16x8*)(ph + 32);
        c2b = *pc2;
      }

      f32x4 a = {q, q, q, q};  // acc pre-loaded with -512*c2[code]
      a = __builtin_amdgcn_mfma_f32_16x16x32_f16(ah0, ch0, a, 0, 0, 0);
      a = __builtin_amdgcn_mfma_f32_16x16x32_f16(ah1, ch1, a, 0, 0, 0);
#pragma unroll
      for (int j = 0; j < 4; ++j) {
        // F = dot*1024 - 512*c2; maximize F <=> minimize dist. Full code in
        // low 10 mantissa bits: <=2^-13 relative shift, absorbed by margin;
        // exact ties always land within margin -> rescored exactly.
        float spf = __uint_as_float((__float_as_uint(a[j]) & 0xFFFFFC00u) | idb);
        float o1 = m1[j], o2 = m2[j];
        m3[j] = __builtin_amdgcn_fmed3f(o2, m3[j], spf);  // 3rd-largest
        m2[j] = __builtin_amdgcn_fmed3f(o1, o2, spf);     // 2nd-largest
        m1[j] = fmaxf(o1, spf);
      }
      idb += 64u;
    }

    // reduce across the 16 code-columns: merge sorted-desc triples
#pragma unroll
    for (int dlt = 1; dlt < 16; dlt <<= 1) {
#pragma unroll
      for (int j = 0; j < 4; ++j) {
        float a1 = m1[j], a2 = m2[j], a3 = m3[j];
        float b1 = __shfl_xor(a1, dlt, 64);
        float b2 = __shfl_xor(a2, dlt, 64);
        float b3 = __shfl_xor(a3, dlt, 64);
        m1[j] = fmaxf(a1, b1);
        m2[j] = fmaxf(fminf(a1, b1), fmaxf(a2, b2));
        m3[j] = fmaxf(fmaxf(fminf(a2, b1), fminf(a1, b2)), fmaxf(a3, b3));
      }
    }

    if (lane15 == 0) {
#pragma unroll
      for (int j = 0; j < 4; ++j) {
        int r = t * 16 + lq * 4 + j;
        int base = (w * 64 + r) * 3;
        red[base + 0] = m1[j];
        red[base + 1] = m2[j];
        red[base + 2] = m3[j];
      }
    }
    // no sync needed: each wave owns its red[w] slice and its A fragments
  }

  __syncthreads();
  if (tid < 64) {
    float a1 = red[tid * 3 + 0], a2 = red[tid * 3 + 1], a3 = red[tid * 3 + 2];
#pragma unroll
    for (int wv = 1; wv < 4; ++wv) {
      float b1 = red[(wv * 64 + tid) * 3 + 0];
      float b2 = red[(wv * 64 + tid) * 3 + 1];
      float b3 = red[(wv * 64 + tid) * 3 + 2];
      float n1 = fmaxf(a1, b1);
      float n2 = fmaxf(fminf(a1, b1), fmaxf(a2, b2));
      float n3 = fmaxf(fmaxf(fminf(a2, b1), fminf(a1, b2)), fmaxf(a3, b3));
      a1 = n1; a2 = n2; a3 = n3;
    }
    unsigned int u1 = __float_as_uint(a1);
    unsigned int u2 = __float_as_uint(a2);
    unsigned int u3 = __float_as_uint(a3);
    int ka = (int)(u1 & 1023u);
    float g1 = __uint_as_float(u1 & 0xFFFFFC00u);
    float g2 = __uint_as_float(u2 & 0xFFFFFC00u);
    float g3 = __uint_as_float(u3 & 0xFFFFFC00u);
    // margin in F-space = 512 * (4.6e-6*Sr + 4.0e-5)  [round-2-validated]
    float margin = __builtin_fmaf(srow[tid], 2.3552e-3f, 2.048e-2f);
    int row = rowbase + tid;
    code_lds[tid] = ka;
    float cf = (float)ka;
    if (g1 - g2 < margin) {
      if (g1 - g3 < margin) {  // clustered: full exact rescore
        unsigned int s = atomicAdd(counters + 0, 1u);
        list[s] = row;
      } else {  // exactly-2 candidates: stash (ka, kb) (exact < 2^20)
        unsigned int s = atomicAdd(counters + 1, 1u);
        list[N - 1 - (int)s] = row;
        cf = (float)(int)((unsigned int)ka | ((u2 & 1023u) << 10));
      }
    }
    codes_f[row] = cf;
  }
  __syncthreads();

  // ---- fused gather (pair/full kernels overwrite their rows if needed)
  for (int e = tid; e < 4096; e += 256) {
    int r = e >> 6, d = e & 63;
    out_q[(size_t)rowbase * D + e] = codebook[((size_t)code_lds[r] << 6) + d];
  }
}

// ---------------- Kernel C: exact np-faithful 2-candidate compare.
__global__ __launch_bounds__(256) void vq_pair(
    const float* __restrict__ residual, const float* __restrict__ codebook,
    const float* __restrict__ c2, float* __restrict__ codes_f,
    float* __restrict__ out_q, const unsigned int* __restrict__ counters,
    const int* __restrict__ list, int N) {
  unsigned int cnt = counters[1];
  for (unsigned int i = blockIdx.x * 256 + threadIdx.x; i < cnt;
       i += gridDim.x * 256) {
    int row = list[N - 1 - (int)i];
    int packed = (int)codes_f[row];
    int ka = packed & 1023, kb = packed >> 10;

    float r[D];
    const float4* rp = (const float4*)(residual + ((size_t)row << 6));
#pragma unroll
    for (int q = 0; q < 16; ++q) {
      float4 v = rp[q];
      r[4 * q] = v.x; r[4 * q + 1] = v.y; r[4 * q + 2] = v.z; r[4 * q + 3] = v.w;
    }
    float r2 = np_sum_sq_64(r);

    float da = 0.f, db = 0.f;
    const float4* ap = (const float4*)(codebook + ((size_t)ka << 6));
    const float4* bp = (const float4*)(codebook + ((size_t)kb << 6));
#pragma unroll
    for (int q = 0; q < 16; ++q) {
      float4 x = ap[q], y = bp[q];
      da = __fmaf_rn(r[4 * q + 0], x.x, da); db = __fmaf_rn(r[4 * q + 0], y.x, db);
      da = __fmaf_rn(r[4 * q + 1], x.y, da); db = __fmaf_rn(r[4 * q + 1], y.y, db);
      da = __fmaf_rn(r[4 * q + 2], x.z, da); db = __fmaf_rn(r[4 * q + 2], y.z, db);
      da = __fmaf_rn(r[4 * q + 3], x.w, da); db = __fmaf_rn(r[4 * q + 3], y.w, db);
    }
    float dista = __fsub_rn(__fadd_rn(r2, c2[ka]), __fmul_rn(2.0f, da));
    float distb = __fsub_rn(__fadd_rn(r2, c2[kb]), __fmul_rn(2.0f, db));
    bool bwin = (distb < dista) || (distb == dista && kb < ka);
    int win = bwin ? kb : ka;
    codes_f[row] = (float)win;  // always: replaces the packed stash
    if (bwin) {  // screen's gather wrote ka's row; fix it
      float4* oq = (float4*)(out_q + ((size_t)row << 6));
      const float4* cw = (const float4*)(codebook + ((size_t)win << 6));
#pragma unroll
      for (int q = 0; q < 16; ++q) oq[q] = cw[q];
    }
  }
}

// ---------------- Kernel D: exact np-faithful full rescore, fully coalesced.
__global__ __launch_bounds__(256) void vq_rescore(
    const float* __restrict__ residual, const float* __restrict__ codebook,
    const float4* __restrict__ cbT4, const float* __restrict__ c2,
    float* __restrict__ codes_f, float* __restrict__ out_q,
    const unsigned int* __restrict__ counters,
    const int* __restrict__ list, int K) {
  unsigned int cnt = counters[0];
  int w = threadIdx.x >> 6, lane = threadIdx.x & 63;
  unsigned int npairs = (cnt + 1) >> 1;
  for (unsigned int g = blockIdx.x * 4 + w; g < npairs; g += gridDim.x * 4) {
    int n0 = list[2 * g];
    bool two = (2 * g + 1 < cnt);
    int n1 = two ? list[2 * g + 1] : n0;

    float rl0 = residual[(size_t)n0 * D + lane];
    float rl1 = residual[(size_t)n1 * D + lane];

    int j = lane & 7;
    float x0 = __shfl(rl0, j, 64), x1 = __shfl(rl1, j, 64);
    float s0 = __fmul_rn(x0, x0), s1 = __fmul_rn(x1, x1);
#pragma unroll
    for (int b = 1; b < 8; ++b) {
      x0 = __shfl(rl0, 8 * b + j, 64);
      x1 = __shfl(rl1, 8 * b + j, 64);
      s0 = __fadd_rn(s0, __fmul_rn(x0, x0));
      s1 = __fadd_rn(s1, __fmul_rn(x1, x1));
    }
    s0 = __fadd_rn(s0, __shfl_xor(s0, 1, 64));
    s1 = __fadd_rn(s1, __shfl_xor(s1, 1, 64));
    s0 = __fadd_rn(s0, __shfl_xor(s0, 2, 64));
    s1 = __fadd_rn(s1, __shfl_xor(s1, 2, 64));
    s0 = __fadd_rn(s0, __shfl_xor(s0, 4, 64));
    s1 = __fadd_rn(s1, __shfl_xor(s1, 4, 64));
    float r2_0 = s0, r2_1 = s1;

    float m0[16], m1v[16];
#pragma unroll
    for (int ch = 0; ch < 16; ++ch) { m0[ch] = 0.f; m1v[ch] = 0.f; }

    for (int d4 = 0; d4 < 16; ++d4) {
      float a0 = __shfl(rl0, 4 * d4, 64), b0 = __shfl(rl0, 4 * d4 + 1, 64);
      float c0 = __shfl(rl0, 4 * d4 + 2, 64), e0 = __shfl(rl0, 4 * d4 + 3, 64);
      float a1 = __shfl(rl1, 4 * d4, 64), b1 = __shfl(rl1, 4 * d4 + 1, 64);
      float c1 = __shfl(rl1, 4 * d4 + 2, 64), e1 = __shfl(rl1, 4 * d4 + 3, 64);
      const float4* bp = cbT4 + (size_t)d4 * K + lane;
      float4 cbv[8];
#pragma unroll
      for (int h = 0; h < 2; ++h) {
#pragma unroll
        for (int q = 0; q < 8; ++q) cbv[q] = bp[(h * 8 + q) * 64];
#pragma unroll
        for (int q = 0; q < 8; ++q) {
          int ch = h * 8 + q;
          float4 c = cbv[q];
          float t0 = m0[ch], t1 = m1v[ch];
          t0 = __fmaf_rn(a0, c.x, t0); t1 = __fmaf_rn(a1, c.x, t1);
          t0 = __fmaf_rn(b0, c.y, t0); t1 = __fmaf_rn(b1, c.y, t1);
          t0 = __fmaf_rn(c0, c.z, t0); t1 = __fmaf_rn(c1, c.z, t1);
          t0 = __fmaf_rn(e0, c.w, t0); t1 = __fmaf_rn(e1, c.w, t1);
          m0[ch] = t0; m1v[ch] = t1;
        }
      }
    }

    float best0 = FLT_MAX, best1 = FLT_MAX;
    int bk0 = 0, bk1 = 0;
#pragma unroll
    for (int ch = 0; ch < 16; ++ch) {
      int code = ch * 64 + lane;
      float c2v = c2[code];
      float d0 = __fsub_rn(__fadd_rn(r2_0, c2v), __fmul_rn(2.0f, m0[ch]));
      float d1 = __fsub_rn(__fadd_rn(r2_1, c2v), __fmul_rn(2.0f, m1v[ch]));
      if (d0 < best0) { best0 = d0; bk0 = code; }
      if (d1 < best1) { best1 = d1; bk1 = code; }
    }
#pragma unroll
    for (int off = 32; off > 0; off >>= 1) {
      float ob = __shfl_down(best0, off, 64);
      int oi = __shfl_down(bk0, off, 64);
      if (ob < best0 || (ob == best0 && oi < bk0)) { best0 = ob; bk0 = oi; }
      ob = __shfl_down(best1, off, 64);
      oi = __shfl_down(bk1, off, 64);
      if (ob < best1 || (ob == best1 && oi < bk1)) { best1 = ob; bk1 = oi; }
    }
    int k0 = __shfl(bk0, 0, 64);
    int k1 = __shfl(bk1, 0, 64);
    if (lane == 0) codes_f[n0] = (float)k0;
    out_q[(size_t)n0 * D + lane] = codebook[((size_t)k0 << 6) + lane];
    if (two) {
      if (lane == 0) codes_f[n1] = (float)k1;
      out_q[(size_t)n1 * D + lane] = codebook[((size_t)k1 << 6) + lane];
    }
  }
}

extern "C" void kernel_launch(void* const* d_in, const int* in_sizes, int n_in,
                              void* d_out, int out_size, void* d_ws, size_t ws_size,
                              hipStream_t stream) {
  const float* residual = (const float*)d_in[0];
  const float* codebook = (const float*)d_in[1];
  int N = in_sizes[0] / D;
  int K = in_sizes[1] / D;

  float* out_q = (float*)d_out;
  float* codes_f = out_q + (size_t)N * D;

  // ws: c2[K] | c2n[K] | cbh fp16[K*D] | cbT4[K*D] | counters[2] | list[N]
  char* ws = (char*)d_ws;
  float* c2 = (float*)ws;
  float* c2n = (float*)(ws + (size_t)K * 4);
  unsigned short* cbh = (unsigned short*)(ws + (size_t)K * 8);
  float4* cbT4 = (float4*)(ws + (size_t)K * 8 + (size_t)K * D * 2);
  unsigned int* counters =
      (unsigned int*)(ws + (size_t)K * 8 + (size_t)K * D * 2 + (size_t)K * D * 4);
  int* list = (int*)(counters + 2);

  vq_prep<<<(K + 63) / 64, 64, 0, stream>>>(codebook, cbh, cbT4, c2, c2n,
                                            counters, K);

  vq_screen<<<N / 64, 256, 0, stream>>>(residual, codebook, cbh, c2n, out_q,
                                        codes_f, counters, list, N, K);

  vq_pair<<<512, 256, 0, stream>>>(residual, codebook, c2, codes_f, out_q,
                                   counters, list, N);

  vq_rescore<<<2048, 256, 0, stream>>>(residual, codebook, cbT4, c2, codes_f,
                                       out_q, counters, list, K);
}

// Round 6
// 246.609 us; speedup vs baseline: 3.0269x; 2.1326x over previous
//
#include <hip/hip_runtime.h>
#include <float.h>

#define D 64

typedef float f32x4 __attribute__((ext_vector_type(4)));
typedef _Float16 f16x8 __attribute__((ext_vector_type(8)));

// numpy pairwise_sum (n=64): 8 stride-interleaved accumulators, tree combine;
// squares rounded separately. Verified bit-exact vs reference in prior rounds.
__device__ __forceinline__ float np_sum_sq_64(const float* v) {
  float s[8];
#pragma unroll
  for (int j = 0; j < 8; ++j) s[j] = __fmul_rn(v[j], v[j]);
#pragma unroll
  for (int b = 1; b < 8; ++b) {
#pragma unroll
    for (int j = 0; j < 8; ++j)
      s[j] = __fadd_rn(s[j], __fmul_rn(v[8 * b + j], v[8 * b + j]));
  }
  float t01 = __fadd_rn(s[0], s[1]);
  float t23 = __fadd_rn(s[2], s[3]);
  float t45 = __fadd_rn(s[4], s[5]);
  float t67 = __fadd_rn(s[6], s[7]);
  return __fadd_rn(__fadd_rn(t01, t23), __fadd_rn(t45, t67));
}

// pack two floats -> two fp16 (RN) in one u32
__device__ __forceinline__ unsigned int pkh(float a, float b) {
  union { _Float16 h[2]; unsigned int u; } x;
  x.h[0] = (_Float16)a;
  x.h[1] = (_Float16)b;
  return x.u;
}

// ---------------- Kernel A: c2[k] np-faithful + fp16 codebook (x1024 scaled,
// keeps all entries fp16-normal) + c2n = -512*c2 (exact) for acc-folding +
// transposed cbT4 for exact rescore.
__global__ __launch_bounds__(64) void vq_prep(
    const float* __restrict__ cb, unsigned short* __restrict__ cbh,
    float4* __restrict__ cbT4, float* __restrict__ c2,
    float* __restrict__ c2n, unsigned int* __restrict__ counters, int K) {
  if (blockIdx.x == 0 && threadIdx.x == 0) { counters[0] = 0u; counters[1] = 0u; }
  int k = blockIdx.x * 64 + threadIdx.x;
  if (k >= K) return;
  float row[D];
  const float4* cp = (const float4*)(cb + (size_t)k * D);
#pragma unroll
  for (int i = 0; i < 16; ++i) {
    float4 v = cp[i];
    row[4 * i] = v.x; row[4 * i + 1] = v.y;
    row[4 * i + 2] = v.z; row[4 * i + 3] = v.w;
    cbT4[(size_t)i * K + k] = v;  // transposed: [d/4][k], lanes k -> coalesced
    *(uint2*)(cbh + (size_t)k * D + 4 * i) =
        make_uint2(pkh(v.x * 1024.f, v.y * 1024.f),
                   pkh(v.z * 1024.f, v.w * 1024.f));
  }
  float c2v = np_sum_sq_64(row);
  c2[k] = c2v;
  c2n[k] = -512.0f * c2v;  // exact (pow-2 scale)
}

// ---------------- Kernel B: fp16 MFMA screen, top-3 tracking, fused gather.
// ROUND-2 t-INNER structure (empirically no-spill: VGPR=64 + AGPR shadow,
// FETCH 35 MB) + max-space acc-folding from round 5 (HW-validated, absmax 0):
// acc init = -512*c2[lane's code], track MAX of F = 1024*dot - 512*c2.
// Per-score epilogue: and_or(id) + med3 + med3 + max (4 VALU, no fma).
// FULL 10-bit code (cc<<6 | w<<4 | lane15) in low mantissa bits -> all
// reduces are pure float max-merges, ids travel inside the values.
// Flag split (F-space): g1-g2 < margin -> pair; also g1-g3 < margin -> full.
__global__ __launch_bounds__(256, 3) void vq_screen(
    const float* __restrict__ residual, const float* __restrict__ codebook,
    const unsigned short* __restrict__ cbh, const float* __restrict__ c2n,
    float* __restrict__ out_q, float* __restrict__ codes_f,
    unsigned int* __restrict__ counters, int* __restrict__ list,
    int N, int K) {
  __shared__ unsigned short smem[4096];  // 8 KB fp16 A tile (fragment-permuted)
  __shared__ float red[768];             // [wave][row(64)][3] triples
  __shared__ int code_lds[64];
  __shared__ float srow[64];             // per-row sum|r| for margin

  int tid = threadIdx.x;
  int rowbase = blockIdx.x * 64;

  // ---- stage 64 rows fp32 -> fp16, fragment-permuted; accumulate sum|r|
  float sr4[4];
#pragma unroll
  for (int jj = 0; jj < 4; ++jj) {
    int i = tid + 256 * jj;
    int r = i >> 4, d0 = (i & 15) * 4;
    float4 v = *(const float4*)(residual + (size_t)(rowbase + r) * D + d0);
    sr4[jj] = fabsf(v.x) + fabsf(v.y) + fabsf(v.z) + fabsf(v.w);
    int tile = r >> 4, rr = r & 15;
    int kblk = d0 >> 5, kk = d0 & 31;
    int lanep = rr + 16 * (kk >> 3);
    int off = ((tile * 2 + kblk) * 64 + lanep) * 8 + (kk & 7);
    *(uint2*)(smem + off) = make_uint2(pkh(v.x, v.y), pkh(v.z, v.w));
  }
#pragma unroll
  for (int jj = 0; jj < 4; ++jj) {
    float s = sr4[jj];
    s += __shfl_xor(s, 1, 64);
    s += __shfl_xor(s, 2, 64);
    s += __shfl_xor(s, 4, 64);
    s += __shfl_xor(s, 8, 64);
    sr4[jj] = s;
  }
  if ((tid & 15) == 0) {
#pragma unroll
    for (int jj = 0; jj < 4; ++jj) srow[(tid >> 4) + 16 * jj] = sr4[jj];
  }
  __syncthreads();

  int w = tid >> 6, lane = tid & 63;
  int lane15 = lane & 15, lq = lane >> 4;

  // A fragments -> registers (ds_read_b128), all 4 tiles resident (round-2)
  f16x8 ah[4][2];
#pragma unroll
  for (int t = 0; t < 4; ++t)
#pragma unroll
    for (int kb = 0; kb < 2; ++kb)
      ah[t][kb] = *(const f16x8*)(smem + ((t * 2 + kb) * 64 + lane) * 8);

  float m1[4][4], m2[4][4], m3[4][4];
#pragma unroll
  for (int t = 0; t < 4; ++t)
#pragma unroll
    for (int j = 0; j < 4; ++j) {
      m1[t][j] = -FLT_MAX; m2[t][j] = -FLT_MAX; m3[t][j] = -FLT_MAX;
    }

  const unsigned short* ph = cbh + (size_t)(w * 16 + lane15) * D + lq * 8;
  const float* pc2 = c2n + (w * 16 + lane15);

  // depth-2 B prefetch: two chunks in flight across the MFMA work
  f16x8 B0a = *(const f16x8*)(ph);
  f16x8 B1a = *(const f16x8*)(ph + 32);
  float c2a = *pc2;
  ph += 64 * D; pc2 += 64;
  f16x8 B0b = *(const f16x8*)(ph);
  f16x8 B1b = *(const f16x8*)(ph + 32);
  float c2b = *pc2;

  unsigned int idb = (unsigned int)((w << 4) | lane15);  // + cc<<6 per chunk
  for (int cc = 0; cc < 16; ++cc) {
    f16x8 ch0 = B0a, ch1 = B1a;
    float q = c2a;
    B0a = B0b; B1a = B1b; c2a = c2b;
    if (cc < 14) {
      ph += 64 * D; pc2 += 64;
      B0b = *(const f16x8*)(ph);
      B1b = *(const f16x8*)(ph + 32);
      c2b = *pc2;
    }

#pragma unroll
    for (int t = 0; t < 4; ++t) {
      f32x4 a = {q, q, q, q};  // acc pre-loaded with -512*c2[lane's code]
      a = __builtin_amdgcn_mfma_f32_16x16x32_f16(ah[t][0], ch0, a, 0, 0, 0);
      a = __builtin_amdgcn_mfma_f32_16x16x32_f16(ah[t][1], ch1, a, 0, 0, 0);
#pragma unroll
      for (int j = 0; j < 4; ++j) {
        // F = dot*1024 - 512*c2; maximize F <=> minimize dist. Full code in
        // low 10 mantissa bits: <=2^-13 relative shift, absorbed by margin;
        // exact ties always land within margin -> rescored exactly.
        float spf = __uint_as_float((__float_as_uint(a[j]) & 0xFFFFFC00u) | idb);
        float o1 = m1[t][j], o2 = m2[t][j];
        m3[t][j] = __builtin_amdgcn_fmed3f(o2, m3[t][j], spf);  // 3rd-largest
        m2[t][j] = __builtin_amdgcn_fmed3f(o1, o2, spf);        // 2nd-largest
        m1[t][j] = fmaxf(o1, spf);
      }
    }
    idb += 64u;
  }

  // reduce across the 16 code-columns: merge sorted-desc triples
#pragma unroll
  for (int dlt = 1; dlt < 16; dlt <<= 1) {
#pragma unroll
    for (int t = 0; t < 4; ++t)
#pragma unroll
      for (int j = 0; j < 4; ++j) {
        float a1 = m1[t][j], a2 = m2[t][j], a3 = m3[t][j];
        float b1 = __shfl_xor(a1, dlt, 64);
        float b2 = __shfl_xor(a2, dlt, 64);
        float b3 = __shfl_xor(a3, dlt, 64);
        m1[t][j] = fmaxf(a1, b1);
        m2[t][j] = fmaxf(fminf(a1, b1), fmaxf(a2, b2));
        m3[t][j] = fmaxf(fmaxf(fminf(a2, b1), fminf(a1, b2)), fmaxf(a3, b3));
      }
  }

  if (lane15 == 0) {
#pragma unroll
    for (int t = 0; t < 4; ++t)
#pragma unroll
      for (int j = 0; j < 4; ++j) {
        int r = t * 16 + lq * 4 + j;
        int base = (w * 64 + r) * 3;
        red[base + 0] = m1[t][j];
        red[base + 1] = m2[t][j];
        red[base + 2] = m3[t][j];
      }
  }
  __syncthreads();
  if (tid < 64) {
    float a1 = red[tid * 3 + 0], a2 = red[tid * 3 + 1], a3 = red[tid * 3 + 2];
#pragma unroll
    for (int wv = 1; wv < 4; ++wv) {
      float b1 = red[(wv * 64 + tid) * 3 + 0];
      float b2 = red[(wv * 64 + tid) * 3 + 1];
      float b3 = red[(wv * 64 + tid) * 3 + 2];
      float n1 = fmaxf(a1, b1);
      float n2 = fmaxf(fminf(a1, b1), fmaxf(a2, b2));
      float n3 = fmaxf(fmaxf(fminf(a2, b1), fminf(a1, b2)), fmaxf(a3, b3));
      a1 = n1; a2 = n2; a3 = n3;
    }
    unsigned int u1 = __float_as_uint(a1);
    unsigned int u2 = __float_as_uint(a2);
    unsigned int u3 = __float_as_uint(a3);
    int ka = (int)(u1 & 1023u);
    float g1 = __uint_as_float(u1 & 0xFFFFFC00u);
    float g2 = __uint_as_float(u2 & 0xFFFFFC00u);
    float g3 = __uint_as_float(u3 & 0xFFFFFC00u);
    // margin in F-space = 512 * (4.6e-6*Sr + 4.0e-5)  [round-2-validated]
    float margin = __builtin_fmaf(srow[tid], 2.3552e-3f, 2.048e-2f);
    int row = rowbase + tid;
    code_lds[tid] = ka;
    float cf = (float)ka;
    if (g1 - g2 < margin) {
      if (g1 - g3 < margin) {  // clustered: full exact rescore
        unsigned int s = atomicAdd(counters + 0, 1u);
        list[s] = row;
      } else {  // exactly-2 candidates: stash (ka, kb) (exact < 2^20)
        unsigned int s = atomicAdd(counters + 1, 1u);
        list[N - 1 - (int)s] = row;
        cf = (float)(int)((unsigned int)ka | ((u2 & 1023u) << 10));
      }
    }
    codes_f[row] = cf;
  }
  __syncthreads();

  // ---- fused gather (pair/full kernels overwrite their rows if needed)
  for (int e = tid; e < 4096; e += 256) {
    int r = e >> 6, d = e & 63;
    out_q[(size_t)rowbase * D + e] = codebook[((size_t)code_lds[r] << 6) + d];
  }
}

// ---------------- Kernel C: exact np-faithful 2-candidate compare.
__global__ __launch_bounds__(256) void vq_pair(
    const float* __restrict__ residual, const float* __restrict__ codebook,
    const float* __restrict__ c2, float* __restrict__ codes_f,
    float* __restrict__ out_q, const unsigned int* __restrict__ counters,
    const int* __restrict__ list, int N) {
  unsigned int cnt = counters[1];
  for (unsigned int i = blockIdx.x * 256 + threadIdx.x; i < cnt;
       i += gridDim.x * 256) {
    int row = list[N - 1 - (int)i];
    int packed = (int)codes_f[row];
    int ka = packed & 1023, kb = packed >> 10;

    float r[D];
    const float4* rp = (const float4*)(residual + ((size_t)row << 6));
#pragma unroll
    for (int q = 0; q < 16; ++q) {
      float4 v = rp[q];
      r[4 * q] = v.x; r[4 * q + 1] = v.y; r[4 * q + 2] = v.z; r[4 * q + 3] = v.w;
    }
    float r2 = np_sum_sq_64(r);

    float da = 0.f, db = 0.f;
    const float4* ap = (const float4*)(codebook + ((size_t)ka << 6));
    const float4* bp = (const float4*)(codebook + ((size_t)kb << 6));
#pragma unroll
    for (int q = 0; q < 16; ++q) {
      float4 x = ap[q], y = bp[q];
      da = __fmaf_rn(r[4 * q + 0], x.x, da); db = __fmaf_rn(r[4 * q + 0], y.x, db);
      da = __fmaf_rn(r[4 * q + 1], x.y, da); db = __fmaf_rn(r[4 * q + 1], y.y, db);
      da = __fmaf_rn(r[4 * q + 2], x.z, da); db = __fmaf_rn(r[4 * q + 2], y.z, db);
      da = __fmaf_rn(r[4 * q + 3], x.w, da); db = __fmaf_rn(r[4 * q + 3], y.w, db);
    }
    float dista = __fsub_rn(__fadd_rn(r2, c2[ka]), __fmul_rn(2.0f, da));
    float distb = __fsub_rn(__fadd_rn(r2, c2[kb]), __fmul_rn(2.0f, db));
    bool bwin = (distb < dista) || (distb == dista && kb < ka);
    int win = bwin ? kb : ka;
    codes_f[row] = (float)win;  // always: replaces the packed stash
    if (bwin) {  // screen's gather wrote ka's row; fix it
      float4* oq = (float4*)(out_q + ((size_t)row << 6));
      const float4* cw = (const float4*)(codebook + ((size_t)win << 6));
#pragma unroll
      for (int q = 0; q < 16; ++q) oq[q] = cw[q];
    }
  }
}

// ---------------- Kernel D: exact np-faithful full rescore, fully coalesced.
__global__ __launch_bounds__(256) void vq_rescore(
    const float* __restrict__ residual, const float* __restrict__ codebook,
    const float4* __restrict__ cbT4, const float* __restrict__ c2,
    float* __restrict__ codes_f, float* __restrict__ out_q,
    const unsigned int* __restrict__ counters,
    const int* __restrict__ list, int K) {
  unsigned int cnt = counters[0];
  int w = threadIdx.x >> 6, lane = threadIdx.x & 63;
  unsigned int npairs = (cnt + 1) >> 1;
  for (unsigned int g = blockIdx.x * 4 + w; g < npairs; g += gridDim.x * 4) {
    int n0 = list[2 * g];
    bool two = (2 * g + 1 < cnt);
    int n1 = two ? list[2 * g + 1] : n0;

    float rl0 = residual[(size_t)n0 * D + lane];
    float rl1 = residual[(size_t)n1 * D + lane];

    int j = lane & 7;
    float x0 = __shfl(rl0, j, 64), x1 = __shfl(rl1, j, 64);
    float s0 = __fmul_rn(x0, x0), s1 = __fmul_rn(x1, x1);
#pragma unroll
    for (int b = 1; b < 8; ++b) {
      x0 = __shfl(rl0, 8 * b + j, 64);
      x1 = __shfl(rl1, 8 * b + j, 64);
      s0 = __fadd_rn(s0, __fmul_rn(x0, x0));
      s1 = __fadd_rn(s1, __fmul_rn(x1, x1));
    }
    s0 = __fadd_rn(s0, __shfl_xor(s0, 1, 64));
    s1 = __fadd_rn(s1, __shfl_xor(s1, 1, 64));
    s0 = __fadd_rn(s0, __shfl_xor(s0, 2, 64));
    s1 = __fadd_rn(s1, __shfl_xor(s1, 2, 64));
    s0 = __fadd_rn(s0, __shfl_xor(s0, 4, 64));
    s1 = __fadd_rn(s1, __shfl_xor(s1, 4, 64));
    float r2_0 = s0, r2_1 = s1;

    float m0[16], m1v[16];
#pragma unroll
    for (int ch = 0; ch < 16; ++ch) { m0[ch] = 0.f; m1v[ch] = 0.f; }

    for (int d4 = 0; d4 < 16; ++d4) {
      float a0 = __shfl(rl0, 4 * d4, 64), b0 = __shfl(rl0, 4 * d4 + 1, 64);
      float c0 = __shfl(rl0, 4 * d4 + 2, 64), e0 = __shfl(rl0, 4 * d4 + 3, 64);
      float a1 = __shfl(rl1, 4 * d4, 64), b1 = __shfl(rl1, 4 * d4 + 1, 64);
      float c1 = __shfl(rl1, 4 * d4 + 2, 64), e1 = __shfl(rl1, 4 * d4 + 3, 64);
      const float4* bp = cbT4 + (size_t)d4 * K + lane;
      float4 cbv[8];
#pragma unroll
      for (int h = 0; h < 2; ++h) {
#pragma unroll
        for (int q = 0; q < 8; ++q) cbv[q] = bp[(h * 8 + q) * 64];
#pragma unroll
        for (int q = 0; q < 8; ++q) {
          int ch = h * 8 + q;
          float4 c = cbv[q];
          float t0 = m0[ch], t1 = m1v[ch];
          t0 = __fmaf_rn(a0, c.x, t0); t1 = __fmaf_rn(a1, c.x, t1);
          t0 = __fmaf_rn(b0, c.y, t0); t1 = __fmaf_rn(b1, c.y, t1);
          t0 = __fmaf_rn(c0, c.z, t0); t1 = __fmaf_rn(c1, c.z, t1);
          t0 = __fmaf_rn(e0, c.w, t0); t1 = __fmaf_rn(e1, c.w, t1);
          m0[ch] = t0; m1v[ch] = t1;
        }
      }
    }

    float best0 = FLT_MAX, best1 = FLT_MAX;
    int bk0 = 0, bk1 = 0;
#pragma unroll
    for (int ch = 0; ch < 16; ++ch) {
      int code = ch * 64 + lane;
      float c2v = c2[code];
      float d0 = __fsub_rn(__fadd_rn(r2_0, c2v), __fmul_rn(2.0f, m0[ch]));
      float d1 = __fsub_rn(__fadd_rn(r2_1, c2v), __fmul_rn(2.0f, m1v[ch]));
      if (d0 < best0) { best0 = d0; bk0 = code; }
      if (d1 < best1) { best1 = d1; bk1 = code; }
    }
#pragma unroll
    for (int off = 32; off > 0; off >>= 1) {
      float ob = __shfl_down(best0, off, 64);
      int oi = __shfl_down(bk0, off, 64);
      if (ob < best0 || (ob == best0 && oi < bk0)) { best0 = ob; bk0 = oi; }
      ob = __shfl_down(best1, off, 64);
      oi = __shfl_down(bk1, off, 64);
      if (ob < best1 || (ob == best1 && oi < bk1)) { best1 = ob; bk1 = oi; }
    }
    int k0 = __shfl(bk0, 0, 64);
    int k1 = __shfl(bk1, 0, 64);
    if (lane == 0) codes_f[n0] = (float)k0;
    out_q[(size_t)n0 * D + lane] = codebook[((size_t)k0 << 6) + lane];
    if (two) {
      if (lane == 0) codes_f[n1] = (float)k1;
      out_q[(size_t)n1 * D + lane] = codebook[((size_t)k1 << 6) + lane];
    }
  }
}

extern "C" void kernel_launch(void* const* d_in, const int* in_sizes, int n_in,
                              void* d_out, int out_size, void* d_ws, size_t ws_size,
                              hipStream_t stream) {
  const float* residual = (const float*)d_in[0];
  const float* codebook = (const float*)d_in[1];
  int N = in_sizes[0] / D;
  int K = in_sizes[1] / D;

  float* out_q = (float*)d_out;
  float* codes_f = out_q + (size_t)N * D;

  // ws: c2[K] | c2n[K] | cbh fp16[K*D] | cbT4[K*D] | counters[2] | list[N]
  char* ws = (char*)d_ws;
  float* c2 = (float*)ws;
  float* c2n = (float*)(ws + (size_t)K * 4);
  unsigned short* cbh = (unsigned short*)(ws + (size_t)K * 8);
  float4* cbT4 = (float4*)(ws + (size_t)K * 8 + (size_t)K * D * 2);
  unsigned int* counters =
      (unsigned int*)(ws + (size_t)K * 8 + (size_t)K * D * 2 + (size_t)K * D * 4);
  int* list = (int*)(counters + 2);

  vq_prep<<<(K + 63) / 64, 64, 0, stream>>>(codebook, cbh, cbT4, c2, c2n,
                                            counters, K);

  vq_screen<<<N / 64, 256, 0, stream>>>(residual, codebook, cbh, c2n, out_q,
                                        codes_f, counters, list, N, K);

  vq_pair<<<512, 256, 0, stream>>>(residual, codebook, c2, codes_f, out_q,
                                   counters, list, N);

  vq_rescore<<<2048, 256, 0, stream>>>(residual, codebook, cbT4, c2, codes_f,
                                       out_q, counters, list, K);
}

// Round 7
// 225.379 us; speedup vs baseline: 3.3120x; 1.0942x over previous
//
#include <hip/hip_runtime.h>
#include <float.h>

#define D 64

typedef float f32x4 __attribute__((ext_vector_type(4)));
typedef _Float16 f16x8 __attribute__((ext_vector_type(8)));

// numpy pairwise_sum (n=64): 8 stride-interleaved accumulators, tree combine;
// squares rounded separately. Verified bit-exact vs reference in prior rounds.
__device__ __forceinline__ float np_sum_sq_64(const float* v) {
  float s[8];
#pragma unroll
  for (int j = 0; j < 8; ++j) s[j] = __fmul_rn(v[j], v[j]);
#pragma unroll
  for (int b = 1; b < 8; ++b) {
#pragma unroll
    for (int j = 0; j < 8; ++j)
      s[j] = __fadd_rn(s[j], __fmul_rn(v[8 * b + j], v[8 * b + j]));
  }
  float t01 = __fadd_rn(s[0], s[1]);
  float t23 = __fadd_rn(s[2], s[3]);
  float t45 = __fadd_rn(s[4], s[5]);
  float t67 = __fadd_rn(s[6], s[7]);
  return __fadd_rn(__fadd_rn(t01, t23), __fadd_rn(t45, t67));
}

// pack two floats -> two fp16 (RN) in one u32
__device__ __forceinline__ unsigned int pkh(float a, float b) {
  union { _Float16 h[2]; unsigned int u; } x;
  x.h[0] = (_Float16)a;
  x.h[1] = (_Float16)b;
  return x.u;
}

// ---------------- Kernel A: c2[k] np-faithful + fp16 codebook (x1024 scaled,
// keeps all entries fp16-normal) + c2n = -512*c2 (exact) for acc-folding +
// transposed cbT4 for exact rescore.
__global__ __launch_bounds__(64) void vq_prep(
    const float* __restrict__ cb, unsigned short* __restrict__ cbh,
    float4* __restrict__ cbT4, float* __restrict__ c2,
    float* __restrict__ c2n, unsigned int* __restrict__ counters, int K) {
  if (blockIdx.x == 0 && threadIdx.x == 0) { counters[0] = 0u; counters[1] = 0u; }
  int k = blockIdx.x * 64 + threadIdx.x;
  if (k >= K) return;
  float row[D];
  const float4* cp = (const float4*)(cb + (size_t)k * D);
#pragma unroll
  for (int i = 0; i < 16; ++i) {
    float4 v = cp[i];
    row[4 * i] = v.x; row[4 * i + 1] = v.y;
    row[4 * i + 2] = v.z; row[4 * i + 3] = v.w;
    cbT4[(size_t)i * K + k] = v;  // transposed: [d/4][k], lanes k -> coalesced
    *(uint2*)(cbh + (size_t)k * D + 4 * i) =
        make_uint2(pkh(v.x * 1024.f, v.y * 1024.f),
                   pkh(v.z * 1024.f, v.w * 1024.f));
  }
  float c2v = np_sum_sq_64(row);
  c2[k] = c2v;
  c2n[k] = -512.0f * c2v;  // exact (pow-2 scale)
}

// ---------------- Kernel B: fp16 MFMA screen, top-3 tracking, INLINE exact
// pair resolution, fused gather. Round-6 hot loop kept byte-identical
// (t-inner, depth-2 B prefetch, max-space acc-folding; HW-validated absmax 0).
// New: rows whose top-2 gap < margin but top-3 gap >= margin (the ~7% "pair"
// case) are resolved IN-KERNEL by the tid<64 wave with the verbatim
// np-faithful 2-candidate compare (masked lanes), BEFORE the fused gather ->
// out_q/codes_f correct first time; vq_pair kernel deleted. Clustered rows
// (both gaps < margin) still go to the full exact rescore list.
__global__ __launch_bounds__(256, 3) void vq_screen(
    const float* __restrict__ residual, const float* __restrict__ codebook,
    const unsigned short* __restrict__ cbh, const float* __restrict__ c2n,
    const float* __restrict__ c2, float* __restrict__ out_q,
    float* __restrict__ codes_f, unsigned int* __restrict__ counters,
    int* __restrict__ list, int N, int K) {
  __shared__ unsigned short smem[4096];  // 8 KB fp16 A tile (fragment-permuted)
  __shared__ float red[768];             // [wave][row(64)][3] triples
  __shared__ int code_lds[64];
  __shared__ float srow[64];             // per-row sum|r| for margin

  int tid = threadIdx.x;
  int rowbase = blockIdx.x * 64;

  // ---- stage 64 rows fp32 -> fp16, fragment-permuted; accumulate sum|r|
  float sr4[4];
#pragma unroll
  for (int jj = 0; jj < 4; ++jj) {
    int i = tid + 256 * jj;
    int r = i >> 4, d0 = (i & 15) * 4;
    float4 v = *(const float4*)(residual + (size_t)(rowbase + r) * D + d0);
    sr4[jj] = fabsf(v.x) + fabsf(v.y) + fabsf(v.z) + fabsf(v.w);
    int tile = r >> 4, rr = r & 15;
    int kblk = d0 >> 5, kk = d0 & 31;
    int lanep = rr + 16 * (kk >> 3);
    int off = ((tile * 2 + kblk) * 64 + lanep) * 8 + (kk & 7);
    *(uint2*)(smem + off) = make_uint2(pkh(v.x, v.y), pkh(v.z, v.w));
  }
#pragma unroll
  for (int jj = 0; jj < 4; ++jj) {
    float s = sr4[jj];
    s += __shfl_xor(s, 1, 64);
    s += __shfl_xor(s, 2, 64);
    s += __shfl_xor(s, 4, 64);
    s += __shfl_xor(s, 8, 64);
    sr4[jj] = s;
  }
  if ((tid & 15) == 0) {
#pragma unroll
    for (int jj = 0; jj < 4; ++jj) srow[(tid >> 4) + 16 * jj] = sr4[jj];
  }
  __syncthreads();

  int w = tid >> 6, lane = tid & 63;
  int lane15 = lane & 15, lq = lane >> 4;

  // A fragments -> registers (ds_read_b128), all 4 tiles resident
  f16x8 ah[4][2];
#pragma unroll
  for (int t = 0; t < 4; ++t)
#pragma unroll
    for (int kb = 0; kb < 2; ++kb)
      ah[t][kb] = *(const f16x8*)(smem + ((t * 2 + kb) * 64 + lane) * 8);

  float m1[4][4], m2[4][4], m3[4][4];
#pragma unroll
  for (int t = 0; t < 4; ++t)
#pragma unroll
    for (int j = 0; j < 4; ++j) {
      m1[t][j] = -FLT_MAX; m2[t][j] = -FLT_MAX; m3[t][j] = -FLT_MAX;
    }

  const unsigned short* ph = cbh + (size_t)(w * 16 + lane15) * D + lq * 8;
  const float* pc2 = c2n + (w * 16 + lane15);

  // depth-2 B prefetch: two chunks in flight across the MFMA work
  f16x8 B0a = *(const f16x8*)(ph);
  f16x8 B1a = *(const f16x8*)(ph + 32);
  float c2a = *pc2;
  ph += 64 * D; pc2 += 64;
  f16x8 B0b = *(const f16x8*)(ph);
  f16x8 B1b = *(const f16x8*)(ph + 32);
  float c2b = *pc2;

  unsigned int idb = (unsigned int)((w << 4) | lane15);  // + cc<<6 per chunk
  for (int cc = 0; cc < 16; ++cc) {
    f16x8 ch0 = B0a, ch1 = B1a;
    float q = c2a;
    B0a = B0b; B1a = B1b; c2a = c2b;
    if (cc < 14) {
      ph += 64 * D; pc2 += 64;
      B0b = *(const f16x8*)(ph);
      B1b = *(const f16x8*)(ph + 32);
      c2b = *pc2;
    }

#pragma unroll
    for (int t = 0; t < 4; ++t) {
      f32x4 a = {q, q, q, q};  // acc pre-loaded with -512*c2[lane's code]
      a = __builtin_amdgcn_mfma_f32_16x16x32_f16(ah[t][0], ch0, a, 0, 0, 0);
      a = __builtin_amdgcn_mfma_f32_16x16x32_f16(ah[t][1], ch1, a, 0, 0, 0);
#pragma unroll
      for (int j = 0; j < 4; ++j) {
        // F = dot*1024 - 512*c2; maximize F <=> minimize dist. Full code in
        // low 10 mantissa bits: <=2^-13 relative shift, absorbed by margin;
        // exact ties always land within margin -> resolved exactly.
        float spf = __uint_as_float((__float_as_uint(a[j]) & 0xFFFFFC00u) | idb);
        float o1 = m1[t][j], o2 = m2[t][j];
        m3[t][j] = __builtin_amdgcn_fmed3f(o2, m3[t][j], spf);  // 3rd-largest
        m2[t][j] = __builtin_amdgcn_fmed3f(o1, o2, spf);        // 2nd-largest
        m1[t][j] = fmaxf(o1, spf);
      }
    }
    idb += 64u;
  }

  // reduce across the 16 code-columns: merge sorted-desc triples
#pragma unroll
  for (int dlt = 1; dlt < 16; dlt <<= 1) {
#pragma unroll
    for (int t = 0; t < 4; ++t)
#pragma unroll
      for (int j = 0; j < 4; ++j) {
        float a1 = m1[t][j], a2 = m2[t][j], a3 = m3[t][j];
        float b1 = __shfl_xor(a1, dlt, 64);
        float b2 = __shfl_xor(a2, dlt, 64);
        float b3 = __shfl_xor(a3, dlt, 64);
        m1[t][j] = fmaxf(a1, b1);
        m2[t][j] = fmaxf(fminf(a1, b1), fmaxf(a2, b2));
        m3[t][j] = fmaxf(fmaxf(fminf(a2, b1), fminf(a1, b2)), fmaxf(a3, b3));
      }
  }

  if (lane15 == 0) {
#pragma unroll
    for (int t = 0; t < 4; ++t)
#pragma unroll
      for (int j = 0; j < 4; ++j) {
        int r = t * 16 + lq * 4 + j;
        int base = (w * 64 + r) * 3;
        red[base + 0] = m1[t][j];
        red[base + 1] = m2[t][j];
        red[base + 2] = m3[t][j];
      }
  }
  __syncthreads();
  if (tid < 64) {
    float a1 = red[tid * 3 + 0], a2 = red[tid * 3 + 1], a3 = red[tid * 3 + 2];
#pragma unroll
    for (int wv = 1; wv < 4; ++wv) {
      float b1 = red[(wv * 64 + tid) * 3 + 0];
      float b2 = red[(wv * 64 + tid) * 3 + 1];
      float b3 = red[(wv * 64 + tid) * 3 + 2];
      float n1 = fmaxf(a1, b1);
      float n2 = fmaxf(fminf(a1, b1), fmaxf(a2, b2));
      float n3 = fmaxf(fmaxf(fminf(a2, b1), fminf(a1, b2)), fmaxf(a3, b3));
      a1 = n1; a2 = n2; a3 = n3;
    }
    unsigned int u1 = __float_as_uint(a1);
    unsigned int u2 = __float_as_uint(a2);
    unsigned int u3 = __float_as_uint(a3);
    int ka = (int)(u1 & 1023u);
    float g1 = __uint_as_float(u1 & 0xFFFFFC00u);
    float g2 = __uint_as_float(u2 & 0xFFFFFC00u);
    float g3 = __uint_as_float(u3 & 0xFFFFFC00u);
    // margin in F-space = 512 * (4.6e-6*Sr + 4.0e-5)  [round-2-validated]
    float margin = __builtin_fmaf(srow[tid], 2.3552e-3f, 2.048e-2f);
    int row = rowbase + tid;
    int win = ka;
    if (g1 - g2 < margin) {
      if (g1 - g3 < margin) {  // clustered: full exact rescore overwrites
        unsigned int s = atomicAdd(counters + 0, 1u);
        list[s] = row;
      } else {
        // exactly-2 candidates: resolve INLINE, verbatim np-faithful compare
        int kb = (int)(u2 & 1023u);
        float r[D];
        const float4* rp = (const float4*)(residual + ((size_t)row << 6));
#pragma unroll
        for (int qq = 0; qq < 16; ++qq) {
          float4 v = rp[qq];
          r[4 * qq] = v.x; r[4 * qq + 1] = v.y;
          r[4 * qq + 2] = v.z; r[4 * qq + 3] = v.w;
        }
        float r2 = np_sum_sq_64(r);
        float da = 0.f, db = 0.f;
        const float4* ap = (const float4*)(codebook + ((size_t)ka << 6));
        const float4* bp = (const float4*)(codebook + ((size_t)kb << 6));
#pragma unroll
        for (int qq = 0; qq < 16; ++qq) {
          float4 x = ap[qq], y = bp[qq];
          da = __fmaf_rn(r[4 * qq + 0], x.x, da); db = __fmaf_rn(r[4 * qq + 0], y.x, db);
          da = __fmaf_rn(r[4 * qq + 1], x.y, da); db = __fmaf_rn(r[4 * qq + 1], y.y, db);
          da = __fmaf_rn(r[4 * qq + 2], x.z, da); db = __fmaf_rn(r[4 * qq + 2], y.z, db);
          da = __fmaf_rn(r[4 * qq + 3], x.w, da); db = __fmaf_rn(r[4 * qq + 3], y.w, db);
        }
        float dista = __fsub_rn(__fadd_rn(r2, c2[ka]), __fmul_rn(2.0f, da));
        float distb = __fsub_rn(__fadd_rn(r2, c2[kb]), __fmul_rn(2.0f, db));
        bool bwin = (distb < dista) || (distb == dista && kb < ka);
        win = bwin ? kb : ka;
      }
    }
    code_lds[tid] = win;
    codes_f[row] = (float)win;
  }
  __syncthreads();

  // ---- fused gather (full-rescore kernel overwrites its rare rows)
  for (int e = tid; e < 4096; e += 256) {
    int r = e >> 6, d = e & 63;
    out_q[(size_t)rowbase * D + e] = codebook[((size_t)code_lds[r] << 6) + d];
  }
}

// ---------------- Kernel C: exact np-faithful full rescore, fully coalesced.
__global__ __launch_bounds__(256) void vq_rescore(
    const float* __restrict__ residual, const float* __restrict__ codebook,
    const float4* __restrict__ cbT4, const float* __restrict__ c2,
    float* __restrict__ codes_f, float* __restrict__ out_q,
    const unsigned int* __restrict__ counters,
    const int* __restrict__ list, int K) {
  unsigned int cnt = counters[0];
  int w = threadIdx.x >> 6, lane = threadIdx.x & 63;
  unsigned int npairs = (cnt + 1) >> 1;
  for (unsigned int g = blockIdx.x * 4 + w; g < npairs; g += gridDim.x * 4) {
    int n0 = list[2 * g];
    bool two = (2 * g + 1 < cnt);
    int n1 = two ? list[2 * g + 1] : n0;

    float rl0 = residual[(size_t)n0 * D + lane];
    float rl1 = residual[(size_t)n1 * D + lane];

    int j = lane & 7;
    float x0 = __shfl(rl0, j, 64), x1 = __shfl(rl1, j, 64);
    float s0 = __fmul_rn(x0, x0), s1 = __fmul_rn(x1, x1);
#pragma unroll
    for (int b = 1; b < 8; ++b) {
      x0 = __shfl(rl0, 8 * b + j, 64);
      x1 = __shfl(rl1, 8 * b + j, 64);
      s0 = __fadd_rn(s0, __fmul_rn(x0, x0));
      s1 = __fadd_rn(s1, __fmul_rn(x1, x1));
    }
    s0 = __fadd_rn(s0, __shfl_xor(s0, 1, 64));
    s1 = __fadd_rn(s1, __shfl_xor(s1, 1, 64));
    s0 = __fadd_rn(s0, __shfl_xor(s0, 2, 64));
    s1 = __fadd_rn(s1, __shfl_xor(s1, 2, 64));
    s0 = __fadd_rn(s0, __shfl_xor(s0, 4, 64));
    s1 = __fadd_rn(s1, __shfl_xor(s1, 4, 64));
    float r2_0 = s0, r2_1 = s1;

    float m0[16], m1v[16];
#pragma unroll
    for (int ch = 0; ch < 16; ++ch) { m0[ch] = 0.f; m1v[ch] = 0.f; }

    for (int d4 = 0; d4 < 16; ++d4) {
      float a0 = __shfl(rl0, 4 * d4, 64), b0 = __shfl(rl0, 4 * d4 + 1, 64);
      float c0 = __shfl(rl0, 4 * d4 + 2, 64), e0 = __shfl(rl0, 4 * d4 + 3, 64);
      float a1 = __shfl(rl1, 4 * d4, 64), b1 = __shfl(rl1, 4 * d4 + 1, 64);
      float c1 = __shfl(rl1, 4 * d4 + 2, 64), e1 = __shfl(rl1, 4 * d4 + 3, 64);
      const float4* bp = cbT4 + (size_t)d4 * K + lane;
      float4 cbv[8];
#pragma unroll
      for (int h = 0; h < 2; ++h) {
#pragma unroll
        for (int q = 0; q < 8; ++q) cbv[q] = bp[(h * 8 + q) * 64];
#pragma unroll
        for (int q = 0; q < 8; ++q) {
          int ch = h * 8 + q;
          float4 c = cbv[q];
          float t0 = m0[ch], t1 = m1v[ch];
          t0 = __fmaf_rn(a0, c.x, t0); t1 = __fmaf_rn(a1, c.x, t1);
          t0 = __fmaf_rn(b0, c.y, t0); t1 = __fmaf_rn(b1, c.y, t1);
          t0 = __fmaf_rn(c0, c.z, t0); t1 = __fmaf_rn(c1, c.z, t1);
          t0 = __fmaf_rn(e0, c.w, t0); t1 = __fmaf_rn(e1, c.w, t1);
          m0[ch] = t0; m1v[ch] = t1;
        }
      }
    }

    float best0 = FLT_MAX, best1 = FLT_MAX;
    int bk0 = 0, bk1 = 0;
#pragma unroll
    for (int ch = 0; ch < 16; ++ch) {
      int code = ch * 64 + lane;
      float c2v = c2[code];
      float d0 = __fsub_rn(__fadd_rn(r2_0, c2v), __fmul_rn(2.0f, m0[ch]));
      float d1 = __fsub_rn(__fadd_rn(r2_1, c2v), __fmul_rn(2.0f, m1v[ch]));
      if (d0 < best0) { best0 = d0; bk0 = code; }
      if (d1 < best1) { best1 = d1; bk1 = code; }
    }
#pragma unroll
    for (int off = 32; off > 0; off >>= 1) {
      float ob = __shfl_down(best0, off, 64);
      int oi = __shfl_down(bk0, off, 64);
      if (ob < best0 || (ob == best0 && oi < bk0)) { best0 = ob; bk0 = oi; }
      ob = __shfl_down(best1, off, 64);
      oi = __shfl_down(bk1, off, 64);
      if (ob < best1 || (ob == best1 && oi < bk1)) { best1 = ob; bk1 = oi; }
    }
    int k0 = __shfl(bk0, 0, 64);
    int k1 = __shfl(bk1, 0, 64);
    if (lane == 0) codes_f[n0] = (float)k0;
    out_q[(size_t)n0 * D + lane] = codebook[((size_t)k0 << 6) + lane];
    if (two) {
      if (lane == 0) codes_f[n1] = (float)k1;
      out_q[(size_t)n1 * D + lane] = codebook[((size_t)k1 << 6) + lane];
    }
  }
}

extern "C" void kernel_launch(void* const* d_in, const int* in_sizes, int n_in,
                              void* d_out, int out_size, void* d_ws, size_t ws_size,
                              hipStream_t stream) {
  const float* residual = (const float*)d_in[0];
  const float* codebook = (const float*)d_in[1];
  int N = in_sizes[0] / D;
  int K = in_sizes[1] / D;

  float* out_q = (float*)d_out;
  float* codes_f = out_q + (size_t)N * D;

  // ws: c2[K] | c2n[K] | cbh fp16[K*D] | cbT4[K*D] | counters[2] | list[N]
  char* ws = (char*)d_ws;
  float* c2 = (float*)ws;
  float* c2n = (float*)(ws + (size_t)K * 4);
  unsigned short* cbh = (unsigned short*)(ws + (size_t)K * 8);
  float4* cbT4 = (float4*)(ws + (size_t)K * 8 + (size_t)K * D * 2);
  unsigned int* counters =
      (unsigned int*)(ws + (size_t)K * 8 + (size_t)K * D * 2 + (size_t)K * D * 4);
  int* list = (int*)(counters + 2);

  vq_prep<<<(K + 63) / 64, 64, 0, stream>>>(codebook, cbh, cbT4, c2, c2n,
                                            counters, K);

  vq_screen<<<N / 64, 256, 0, stream>>>(residual, codebook, cbh, c2n, c2,
                                        out_q, codes_f, counters, list, N, K);

  vq_rescore<<<512, 256, 0, stream>>>(residual, codebook, cbT4, c2, codes_f,
                                      out_q, counters, list, K);
}